// Round 9
// baseline (302.368 us; speedup 1.0000x reference)
//
#include <hip/hip_runtime.h>

#define HIDDEN 64

typedef float f32x4 __attribute__((ext_vector_type(4)));
typedef short bf16x8 __attribute__((ext_vector_type(8)));
typedef unsigned int u32x4 __attribute__((ext_vector_type(4)));

union U8 {
    bf16x8 v;
    unsigned short s[8];
    unsigned int d[4];
};

__device__ __forceinline__ float lane_bcast(float v, int l) {
    return __uint_as_float(__builtin_amdgcn_readlane(__float_as_uint(v), l));
}

// bf16 round-to-nearest-even pack/unpack
__device__ __forceinline__ unsigned int f2b(float f) {
    unsigned int u = __float_as_uint(f);
    return (u + 0x7FFFu + ((u >> 16) & 1u)) >> 16;
}
__device__ __forceinline__ float b2f(unsigned int v) {
    return __uint_as_float(v << 16);
}

// =====================  x -> bf16 convert  =====================
__global__ __launch_bounds__(256) void xcvt_kernel(const float4* __restrict__ x,
                                                   ushort4* __restrict__ x16, int n4) {
    int i = blockIdx.x * blockDim.x + threadIdx.x;
    const int st = gridDim.x * blockDim.x;
    for (; i < n4; i += st) {
        const float4 v = x[i];
        ushort4 o;
        o.x = (unsigned short)f2b(v.x);
        o.y = (unsigned short)f2b(v.y);
        o.z = (unsigned short)f2b(v.z);
        o.w = (unsigned short)f2b(v.w);
        x16[i] = o;
    }
}

// =====================  CSR-build kernels (per-node exact)  =====================

__global__ __launch_bounds__(256) void hist_kernel(const int* __restrict__ ei, int* __restrict__ cnt,
                                                   int E) {
    int i = blockIdx.x * blockDim.x + threadIdx.x;
    int stride = gridDim.x * blockDim.x;
    for (; i < E; i += stride) atomicAdd(&cnt[__builtin_nontemporal_load(&ei[E + i])], 1);
}

__global__ __launch_bounds__(256) void scan1_kernel(int* __restrict__ cnt, int* __restrict__ partial,
                                                    int N) {
    __shared__ int s[256];
    const int t = threadIdx.x;
    const int base = blockIdx.x * 1024 + t * 4;
    int v0 = (base + 0 < N) ? cnt[base + 0] : 0;
    int v1 = (base + 1 < N) ? cnt[base + 1] : 0;
    int v2 = (base + 2 < N) ? cnt[base + 2] : 0;
    int v3 = (base + 3 < N) ? cnt[base + 3] : 0;
    const int mysum = v0 + v1 + v2 + v3;
    s[t] = mysum;
    __syncthreads();
    for (int d = 1; d < 256; d <<= 1) {
        int u = (t >= d) ? s[t - d] : 0;
        __syncthreads();
        s[t] += u;
        __syncthreads();
    }
    const int excl = s[t] - mysum;
    if (base + 0 < N) cnt[base + 0] = excl;
    if (base + 1 < N) cnt[base + 1] = excl + v0;
    if (base + 2 < N) cnt[base + 2] = excl + v0 + v1;
    if (base + 3 < N) cnt[base + 3] = excl + v0 + v1 + v2;
    if (t == 255) partial[blockIdx.x] = s[255];
}

__global__ __launch_bounds__(256) void scan2_kernel(int* __restrict__ partial, int nb) {
    __shared__ int s[256];
    const int t = threadIdx.x;
    const int mysum = (t < nb) ? partial[t] : 0;
    s[t] = mysum;
    __syncthreads();
    for (int d = 1; d < 256; d <<= 1) {
        int u = (t >= d) ? s[t - d] : 0;
        __syncthreads();
        s[t] += u;
        __syncthreads();
    }
    if (t < nb) partial[t] = s[t] - mysum;
}

__global__ __launch_bounds__(256) void scan3_kernel(int* __restrict__ off, int* __restrict__ cur,
                                                    const int* __restrict__ partial, int N, int E) {
    int i = blockIdx.x * blockDim.x + threadIdx.x;
    if (i < N) {
        const int o = off[i] + partial[i >> 10];
        off[i] = o;
        cur[i] = o;
    }
    if (i == 0) off[N] = E;
}

// XCD-partitioned scatter, 16-B single-store records, NT memory ops.
// rec = {src, ea01_bf16, ea23_bf16, 0}. NT store -> write bytes ~= payload
// (no partial-line evict/refetch); NT loads -> no L2 pollution.
__global__ __launch_bounds__(256) void scatter_fold_kernel(const int* __restrict__ ei,
                                                           const float* __restrict__ ea,
                                                           int* __restrict__ cur,
                                                           u32x4* __restrict__ recs, int E, int N) {
    const int grp = blockIdx.x & 7;
    const int gblk = blockIdx.x >> 3;
    const int nblk = gridDim.x >> 3;
    const int lo = (int)((long long)grp * N / 8);
    const int hi = (int)((long long)(grp + 1) * N / 8);
    int i = gblk * blockDim.x + threadIdx.x;
    const int st = nblk * blockDim.x;
    for (; i < E; i += st) {
        const int dst = __builtin_nontemporal_load(&ei[E + i]);
        if (dst >= lo && dst < hi) {
            const int src = __builtin_nontemporal_load(&ei[i]);
            const f32x4 a = __builtin_nontemporal_load((const f32x4*)&ea[(size_t)i * 4]);
            const int slot = atomicAdd(&cur[dst], 1);
            u32x4 r;
            r.x = (unsigned int)src;
            r.y = f2b(a.x) | (f2b(a.y) << 16);
            r.z = f2b(a.z) | (f2b(a.w) << 16);
            r.w = 0u;
            __builtin_nontemporal_store(r, &recs[slot]);
        }
    }
}

// =====================  gather (bf16 x, 16-B records)  =====================
__global__ __launch_bounds__(256) void gather16_kernel(
    const float* __restrict__ x, const unsigned short* __restrict__ x16,
    const int* __restrict__ off, const u32x4* __restrict__ recs,
    const float* __restrict__ We, const float* __restrict__ be, float* __restrict__ hout, int N) {
    const int lane = threadIdx.x & 63;
    const float w0 = We[lane];
    const float w1 = We[64 + lane];
    const float w2 = We[128 + lane];
    const float w3 = We[192 + lane];
    const float bb = be[lane];
    int wave = (blockIdx.x * blockDim.x + threadIdx.x) >> 6;
    const int nw = (gridDim.x * blockDim.x) >> 6;
    for (int n = wave; n < N; n += nw) {
        const int s0 = off[n];
        const int s1 = off[n + 1];
        float acc = x[(size_t)n * HIDDEN + lane];
        int s = s0;
        for (; s + 4 <= s1; s += 4) {
            const u32x4 r0 = __builtin_nontemporal_load(&recs[s + 0]);
            const u32x4 r1 = __builtin_nontemporal_load(&recs[s + 1]);
            const u32x4 r2 = __builtin_nontemporal_load(&recs[s + 2]);
            const u32x4 r3 = __builtin_nontemporal_load(&recs[s + 3]);
            const float x0 = b2f(x16[(size_t)r0.x * HIDDEN + lane]);
            const float x1 = b2f(x16[(size_t)r1.x * HIDDEN + lane]);
            const float x2 = b2f(x16[(size_t)r2.x * HIDDEN + lane]);
            const float x3 = b2f(x16[(size_t)r3.x * HIDDEN + lane]);
            acc += fmaxf(x0 + (bb + b2f(r0.y & 0xFFFFu) * w0 + b2f(r0.y >> 16) * w1 +
                               b2f(r0.z & 0xFFFFu) * w2 + b2f(r0.z >> 16) * w3), 0.0f);
            acc += fmaxf(x1 + (bb + b2f(r1.y & 0xFFFFu) * w0 + b2f(r1.y >> 16) * w1 +
                               b2f(r1.z & 0xFFFFu) * w2 + b2f(r1.z >> 16) * w3), 0.0f);
            acc += fmaxf(x2 + (bb + b2f(r2.y & 0xFFFFu) * w0 + b2f(r2.y >> 16) * w1 +
                               b2f(r2.z & 0xFFFFu) * w2 + b2f(r2.z >> 16) * w3), 0.0f);
            acc += fmaxf(x3 + (bb + b2f(r3.y & 0xFFFFu) * w0 + b2f(r3.y >> 16) * w1 +
                               b2f(r3.z & 0xFFFFu) * w2 + b2f(r3.z >> 16) * w3), 0.0f);
        }
        for (; s < s1; ++s) {
            const u32x4 r = __builtin_nontemporal_load(&recs[s]);
            const float xv = b2f(x16[(size_t)r.x * HIDDEN + lane]);
            acc += fmaxf(xv + (bb + b2f(r.y & 0xFFFFu) * w0 + b2f(r.y >> 16) * w1 +
                               b2f(r.z & 0xFFFFu) * w2 + b2f(r.z >> 16) * w3), 0.0f);
        }
        hout[(size_t)n * HIDDEN + lane] = acc;
    }
}

// =====================  MLP via MFMA (in-place on hio)  =====================
// Wave processes 16 nodes. Computes out^T = W^T @ h^T per layer:
//   A-frag  = W-transpose tile: a[ct][kk].s[j] = W[kk*32+g*8+j][ct*16+c]
//   B-frag  = h rows (bf16x8 contiguous in k)
//   C layout (16x16x32): col=lane&15 -> node, row=(lane>>4)*4+reg -> out channel
// Inter-layer transpose through a per-wave padded LDS tile (stride 144 B).
__global__ __launch_bounds__(256) void mlp_mfma_kernel(float* __restrict__ hio,
                                                       const float* __restrict__ W1,
                                                       const float* __restrict__ b1,
                                                       const float* __restrict__ W2,
                                                       const float* __restrict__ b2, int N) {
    __shared__ unsigned short tlds[4][16 * 72];  // per-wave 16 rows x 72 ushort (144 B stride)
    const int lane = threadIdx.x & 63;
    const int wid = threadIdx.x >> 6;
    const int g = lane >> 4;   // 0..3
    const int c = lane & 15;   // 0..15

    // Preload W^T fragments and bias slices (per-wave constants)
    U8 a1[4][2], a2[4][2];
#pragma unroll
    for (int ct = 0; ct < 4; ++ct)
#pragma unroll
        for (int kk = 0; kk < 2; ++kk)
#pragma unroll
            for (int j = 0; j < 8; ++j) {
                a1[ct][kk].s[j] = (unsigned short)f2b(W1[(kk * 32 + g * 8 + j) * 64 + ct * 16 + c]);
                a2[ct][kk].s[j] = (unsigned short)f2b(W2[(kk * 32 + g * 8 + j) * 64 + ct * 16 + c]);
            }
    float b1c[4][4], b2c[4][4];
#pragma unroll
    for (int ct = 0; ct < 4; ++ct)
#pragma unroll
        for (int r = 0; r < 4; ++r) {
            b1c[ct][r] = b1[ct * 16 + g * 4 + r];
            b2c[ct][r] = b2[ct * 16 + g * 4 + r];
        }

    unsigned char* myb = (unsigned char*)&tlds[wid][0];

    const int tile = blockIdx.x * 4 + wid;
    const int ntiles = (N + 15) >> 4;
    if (tile >= ntiles) return;
    const int base = tile * 16;
    const int row = base + c;
    const int rowc = min(row, N - 1);

    // Layer 1: load h rows as B-frags (f32 -> bf16), mfma
    U8 b1f[2];
#pragma unroll
    for (int kk = 0; kk < 2; ++kk) {
        const float4* hp = (const float4*)&hio[(size_t)rowc * 64 + kk * 32 + g * 8];
        const float4 lo = hp[0];
        const float4 hi = hp[1];
        b1f[kk].d[0] = f2b(lo.x) | (f2b(lo.y) << 16);
        b1f[kk].d[1] = f2b(lo.z) | (f2b(lo.w) << 16);
        b1f[kk].d[2] = f2b(hi.x) | (f2b(hi.y) << 16);
        b1f[kk].d[3] = f2b(hi.z) | (f2b(hi.w) << 16);
    }
    f32x4 acc1[4];
#pragma unroll
    for (int ct = 0; ct < 4; ++ct) {
        acc1[ct] = (f32x4)(0.0f);
#pragma unroll
        for (int kk = 0; kk < 2; ++kk)
            acc1[ct] = __builtin_amdgcn_mfma_f32_16x16x32_bf16(a1[ct][kk].v, b1f[kk].v, acc1[ct], 0, 0, 0);
    }

    // bias + relu, pack bf16 pairs into LDS transpose tile [node][oc1] (stride 144 B)
#pragma unroll
    for (int ct = 0; ct < 4; ++ct)
#pragma unroll
        for (int rp = 0; rp < 2; ++rp) {
            const float v0 = fmaxf(acc1[ct][2 * rp + 0] + b1c[ct][2 * rp + 0], 0.0f);
            const float v1 = fmaxf(acc1[ct][2 * rp + 1] + b1c[ct][2 * rp + 1], 0.0f);
            *(unsigned int*)(myb + c * 144 + ct * 32 + g * 8 + rp * 4) = f2b(v0) | (f2b(v1) << 16);
        }

    // Layer 2: read B2-frags from LDS (contiguous 16 B per lane), mfma
    U8 b2f_[2];
#pragma unroll
    for (int kk2 = 0; kk2 < 2; ++kk2) {
        const unsigned int* q = (const unsigned int*)(myb + c * 144 + kk2 * 64 + g * 16);
        b2f_[kk2].d[0] = q[0];
        b2f_[kk2].d[1] = q[1];
        b2f_[kk2].d[2] = q[2];
        b2f_[kk2].d[3] = q[3];
    }
    f32x4 acc2[4];
#pragma unroll
    for (int ct = 0; ct < 4; ++ct) {
        acc2[ct] = (f32x4)(0.0f);
#pragma unroll
        for (int kk2 = 0; kk2 < 2; ++kk2)
            acc2[ct] = __builtin_amdgcn_mfma_f32_16x16x32_bf16(a2[ct][kk2].v, b2f_[kk2].v, acc2[ct], 0, 0, 0);
    }

    // store out[node][oc2] = acc2 + b2 (in place; wave already consumed its rows)
    if (row < N) {
#pragma unroll
        for (int ct = 0; ct < 4; ++ct)
#pragma unroll
            for (int r = 0; r < 4; ++r)
                hio[(size_t)row * 64 + ct * 16 + g * 4 + r] = acc2[ct][r] + b2c[ct][r];
    }
}

// =====================  readlane MLP (fallback path only)  =====================
__global__ __launch_bounds__(256) void mlp_kernel(const float* __restrict__ hin,
                                                  const float* __restrict__ W1,
                                                  const float* __restrict__ b1,
                                                  const float* __restrict__ W2,
                                                  const float* __restrict__ b2,
                                                  float* __restrict__ out, int N) {
    const int lane = threadIdx.x & 63;
    float w1c[64], w2c[64];
#pragma unroll
    for (int k = 0; k < 64; ++k) w1c[k] = W1[k * 64 + lane];
#pragma unroll
    for (int k = 0; k < 64; ++k) w2c[k] = W2[k * 64 + lane];
    const float bb1 = b1[lane];
    const float bb2 = b2[lane];
    int wave = (blockIdx.x * blockDim.x + threadIdx.x) >> 6;
    const int nw = (gridDim.x * blockDim.x) >> 6;
    for (int n = wave; n < N; n += nw) {
        const float h = hin[(size_t)n * HIDDEN + lane];
        float t0 = bb1, t1 = 0.0f;
#pragma unroll
        for (int k = 0; k < 64; k += 2) {
            t0 = fmaf(lane_bcast(h, k), w1c[k], t0);
            t1 = fmaf(lane_bcast(h, k + 1), w1c[k + 1], t1);
        }
        const float t = fmaxf(t0 + t1, 0.0f);
        float o0 = bb2, o1 = 0.0f;
#pragma unroll
        for (int k = 0; k < 64; k += 2) {
            o0 = fmaf(lane_bcast(t, k), w2c[k], o0);
            o1 = fmaf(lane_bcast(t, k + 1), w2c[k + 1], o1);
        }
        out[(size_t)n * HIDDEN + lane] = o0 + o1;
    }
}

// =====================  fallback (ws too small): atomic path, fp32  =====================
__global__ __launch_bounds__(256) void gine_copy_kernel(const float4* __restrict__ x,
                                                        float4* __restrict__ out, int n4) {
    int i = blockIdx.x * blockDim.x + threadIdx.x;
    int stride = gridDim.x * blockDim.x;
    for (; i < n4; i += stride) out[i] = x[i];
}

__global__ __launch_bounds__(256) void gine_edge_kernel(const float* __restrict__ x,
                                                        const int* __restrict__ ei,
                                                        const float4* __restrict__ ea,
                                                        const float* __restrict__ We,
                                                        const float* __restrict__ be,
                                                        float* __restrict__ out, int E) {
    const int lane = threadIdx.x & 63;
    const float w0 = We[lane];
    const float w1 = We[64 + lane];
    const float w2 = We[128 + lane];
    const float w3 = We[192 + lane];
    const float bb = be[lane];
    int wave = (blockIdx.x * blockDim.x + threadIdx.x) >> 6;
    const int nw = (gridDim.x * blockDim.x) >> 6;
    for (int e = wave; e < E; e += nw) {
        const int src = ei[e];
        const int dst = ei[E + e];
        const float4 a = ea[e];
        float m = x[src * HIDDEN + lane] + (bb + a.x * w0 + a.y * w1 + a.z * w2 + a.w * w3);
        m = fmaxf(m, 0.0f);
        atomicAdd(out + dst * HIDDEN + lane, m);
    }
}

extern "C" void kernel_launch(void* const* d_in, const int* in_sizes, int n_in,
                              void* d_out, int out_size, void* d_ws, size_t ws_size,
                              hipStream_t stream) {
    const float* x  = (const float*)d_in[0];
    const int*   ei = (const int*)d_in[1];
    const float* ea = (const float*)d_in[2];
    const float* We = (const float*)d_in[3];
    const float* be = (const float*)d_in[4];
    const float* W1 = (const float*)d_in[5];
    const float* b1 = (const float*)d_in[6];
    const float* W2 = (const float*)d_in[7];
    const float* b2 = (const float*)d_in[8];
    float* out = (float*)d_out;

    const int N = in_sizes[0] / HIDDEN;  // 100000
    const int E = in_sizes[1] / 2;       // 1600000

    // Workspace layout (h lives in d_out between gather and mlp)
    const size_t off_bytes = (size_t)(N + 1) * 4;
    size_t p = 0;
    const size_t off_ofs  = p; p += (off_bytes + 255) & ~(size_t)255;
    const size_t cur_ofs  = p; p += ((size_t)N * 4 + 255) & ~(size_t)255;
    const size_t part_ofs = p; p += 512 * 4;
    const size_t rec_ofs  = p; p += (size_t)E * 16;
    const size_t x16_ofs  = p; p += ((size_t)N * HIDDEN * 2 + 255) & ~(size_t)255;
    const size_t need = p;

    if (ws_size < need) {
        gine_copy_kernel<<<2048, 256, 0, stream>>>((const float4*)x, (float4*)out,
                                                   N * (HIDDEN / 4));
        gine_edge_kernel<<<2048, 256, 0, stream>>>(x, ei, (const float4*)ea, We, be, out, E);
        mlp_kernel<<<2048, 256, 0, stream>>>(out, W1, b1, W2, b2, out, N);
        return;
    }

    char* ws = (char*)d_ws;
    int*            off  = (int*)(ws + off_ofs);
    int*            cur  = (int*)(ws + cur_ofs);
    int*            part = (int*)(ws + part_ofs);
    u32x4*          recs = (u32x4*)(ws + rec_ofs);
    unsigned short* x16  = (unsigned short*)(ws + x16_ofs);

    const int nb_scan = (N + 1023) / 1024;  // <= 256 for N <= 262144

    xcvt_kernel<<<2048, 256, 0, stream>>>((const float4*)x, (ushort4*)x16, N * (HIDDEN / 4));
    hipMemsetAsync(off, 0, off_bytes, stream);
    hist_kernel<<<2048, 256, 0, stream>>>(ei, off, E);
    scan1_kernel<<<nb_scan, 256, 0, stream>>>(off, part, N);
    scan2_kernel<<<1, 256, 0, stream>>>(part, nb_scan);
    scan3_kernel<<<(N + 255) / 256, 256, 0, stream>>>(off, cur, part, N, E);
    scatter_fold_kernel<<<2048, 256, 0, stream>>>(ei, ea, cur, recs, E, N);
    gather16_kernel<<<2048, 256, 0, stream>>>(x, x16, off, recs, We, be, out, N);
    const int ntiles = (N + 15) / 16;
    mlp_mfma_kernel<<<(ntiles + 3) / 4, 256, 0, stream>>>(out, W1, b1, W2, b2, N);
}